// Round 4
// baseline (249.640 us; speedup 1.0000x reference)
//
#include <hip/hip_runtime.h>
#include <hip/hip_bf16.h>
#include <math.h>

#define BATCH_N 8
#define SEQ_T   2048
#define DIM_D   1024
#define HS_N    128

using bf16x8_t = __attribute__((ext_vector_type(8))) __bf16;
using bf16x4_t = __attribute__((ext_vector_type(4))) __bf16;
using f32x4_t  = __attribute__((ext_vector_type(4))) float;

__device__ __forceinline__ f32x4_t mfma_16x16x32(bf16x8_t a, bf16x8_t b, f32x4_t c) {
  return __builtin_amdgcn_mfma_f32_16x16x32_bf16(a, b, c, 0, 0, 0);
}

// async global->LDS, 16B/lane; LDS dest = wave-uniform base + lane*16
__device__ __forceinline__ void async_cp16(const void* g, void* l) {
  __builtin_amdgcn_global_load_lds(
      (const __attribute__((address_space(1))) unsigned int*)g,
      (__attribute__((address_space(3))) unsigned int*)l, 16, 0, 0);
}

// Counted-vmcnt barrier discipline (T4): never drain vmcnt(0) in main loops.
#define BAR()      __builtin_amdgcn_s_barrier()
#define FENCE()    asm volatile("" ::: "memory")
#define WAIT_VM(n) asm volatile("s_waitcnt vmcnt(" #n ")" ::: "memory")
#define WAIT_LGKM0 asm volatile("s_waitcnt lgkmcnt(0)" ::: "memory")

// ---------------------------------------------------------------------------
// Kernel 0: cast W -> bf16, rows [K:0-127][Q:128-255][V:256-383], Q pre-scaled.
// Also zeroes km and the 128 merge counters.
// ---------------------------------------------------------------------------
__global__ __launch_bounds__(256) void castw_kernel(
    const float* __restrict__ Wk, const float* __restrict__ Wq,
    const float* __restrict__ Wv, __bf16* __restrict__ Wb,
    unsigned int* __restrict__ km, unsigned int* __restrict__ cnt) {
  if (blockIdx.x == 0) {
    if (threadIdx.x < 8) km[threadIdx.x] = 0u;
    if (threadIdx.x < 128) cnt[threadIdx.x] = 0u;
  }
  int idx = blockIdx.x * 256 + threadIdx.x;
  int e   = idx * 4;
  int row = e >> 10;
  int col = e & 1023;
  const float* src;
  float sc = 1.0f;
  if (row < 128) {
    src = Wk + row * DIM_D + col;
  } else if (row < 256) {
    src = Wq + (row - 128) * DIM_D + col;
    sc  = 0.08838834764831845f;  // 1/sqrt(HS) folded into Wq
  } else {
    src = Wv + (row - 256) * DIM_D + col;
  }
  float4 v = *(const float4*)src;
  bf16x4_t o;
  o[0] = (__bf16)(v.x * sc); o[1] = (__bf16)(v.y * sc);
  o[2] = (__bf16)(v.z * sc); o[3] = (__bf16)(v.w * sc);
  *(bf16x4_t*)(Wb + e) = o;
}

// ---------------------------------------------------------------------------
// Kernel 1: projections v13 — v12 + triple-buffered B (2-iter latency cover)
// + fused knorm epilogue (per-batch max ||k||^2 via in-register acc).
// M=64 rows/block, 512 threads (8 waves = 2 m-halves x 4 n-groups), grid 256.
// B staging: stage(kt+2) each iter into buf[(kt+2)%3]; steady-state
// s_waitcnt vmcnt(6) (2 batches x 3 loads in flight), tail 3/0.
// LDS = 65536 (A: 64x512/phase) + 3x24576 (B tbuf) = 139264 -> 1 block/CU.
// Accumulation order per output unchanged -> bit-identical Q/K/V.
// ---------------------------------------------------------------------------
__global__ __launch_bounds__(512, 1) void proj_kernel(
    const float* __restrict__ x, const __bf16* __restrict__ Wb,
    __bf16* __restrict__ Qb, __bf16* __restrict__ Kb, __bf16* __restrict__ Vt,
    unsigned int* __restrict__ km) {
  __shared__ __align__(16) char psmem[139264];
  __bf16* A = (__bf16*)psmem;                       // 64 x 512 bf16 = 64 KB

  const int tid  = threadIdx.x;
  const int lane = tid & 63;
  const int wave = tid >> 6;     // 0..7
  const int h    = wave >> 2;    // m-half (0..1)
  const int g    = wave & 3;     // n-group (0..3)
  const int lr = lane & 15;
  const int lq = lane >> 4;
  const int m0 = blockIdx.x * 64;

  f32x4_t acc[2][6];
  #pragma unroll
  for (int mt = 0; mt < 2; ++mt)
    #pragma unroll
    for (int nt = 0; nt < 6; ++nt) acc[mt][nt] = (f32x4_t){0.f, 0.f, 0.f, 0.f};

  auto stageB = [&](int kt) {
    __bf16* Bs = (__bf16*)(psmem + 65536 + (kt % 3) * 24576);
    for (int c = wave; c < 24; c += 8) {     // 3 x 16B loads per wave
      const int row = c * 16 + (lane >> 2);
      const int u   = (lane & 3) ^ ((row >> 1) & 3);
      async_cp16(Wb + (size_t)row * DIM_D + kt * 32 + u * 8, Bs + c * 512);
    }
  };

  stageB(0);
  stageB(1);

  for (int p = 0; p < 2; ++p) {
    __syncthreads();   // phase boundary: full drain OK (2x/kernel)

    // ---- cast this phase's x slab (64 rows x 512 cols) fp32->bf16 into LDS ----
    {
      const int r  = tid >> 3;        // 0..63
      const int t  = tid & 7;
      const float* xs = x + (size_t)(m0 + r) * DIM_D + p * 512;
      __bf16* as = A + r * 512;
      const int sw = r & 7;
      #pragma unroll
      for (int i = 0; i < 8; ++i) {
        const int u = t + 8 * i;      // 16B units (8 bf16) within the phase
        float4 f0 = *(const float4*)(xs + u * 8);
        float4 f1 = *(const float4*)(xs + u * 8 + 4);
        bf16x8_t a;
        a[0] = (__bf16)f0.x; a[1] = (__bf16)f0.y;
        a[2] = (__bf16)f0.z; a[3] = (__bf16)f0.w;
        a[4] = (__bf16)f1.x; a[5] = (__bf16)f1.y;
        a[6] = (__bf16)f1.z; a[7] = (__bf16)f1.w;
        *(bf16x8_t*)(as + ((u ^ sw) * 8)) = a;
      }
    }
    __syncthreads();   // A ready

    for (int kt2 = 0; kt2 < 16; ++kt2) {
      const int kt = p * 16 + kt2;
      if (kt + 2 < 32) stageB(kt + 2);   // depth-2 prefetch stays in flight
      if (kt < 30)       { WAIT_VM(6); } // batches kt+1, kt+2 in flight
      else if (kt == 30) { WAIT_VM(3); } // only batch 31 younger
      else               { WAIT_VM(0); }
      BAR();                             // all waves: buf[kt%3] fully written
      FENCE();
      const __bf16* Bs = (const __bf16*)(psmem + 65536 + (kt % 3) * 24576);

      bf16x8_t af[2];
      #pragma unroll
      for (int mt = 0; mt < 2; ++mt) {
        const int ml = h * 32 + mt * 16 + lr;
        const int u  = kt2 * 4 + lq;
        af[mt] = *(const bf16x8_t*)(&A[ml * 512 + ((u ^ (ml & 7)) * 8)]);
      }
      bf16x8_t bfv[6];
      #pragma unroll
      for (int nt = 0; nt < 6; ++nt) {
        const int nl = g * 96 + nt * 16 + lr;
        bfv[nt] = *(const bf16x8_t*)(&Bs[nl * 32 + ((lq ^ ((nl >> 1) & 3)) * 8)]);
      }
      #pragma unroll
      for (int mt = 0; mt < 2; ++mt)
        #pragma unroll
        for (int nt = 0; nt < 6; ++nt)
          acc[mt][nt] = mfma_16x16x32(af[mt], bfv[nt], acc[mt][nt]);
      WAIT_LGKM0;                    // my LDS reads landed in regs
      BAR();                         // release buf[(kt+2)%3] target for next iter
      FENCE();
    }
  }

  // ---- fused knorm: this block computes ALL 128 K-cols of rows m0..m0+63 ----
  __syncthreads();
  float* rowss = (float*)psmem;      // A region dead; reuse 64 floats
  if (tid < 64) rowss[tid] = 0.f;
  __syncthreads();
  if (g < 2) {                       // K cols live in g=0 (0..95), g=1 nt<2 (96..127)
    #pragma unroll
    for (int mt = 0; mt < 2; ++mt)
      #pragma unroll
      for (int r = 0; r < 4; ++r) {
        float s = 0.f;
        #pragma unroll
        for (int nt = 0; nt < 6; ++nt)
          if (g == 0 || nt < 2) s += acc[mt][nt][r] * acc[mt][nt][r];
        s += __shfl_xor(s, 1); s += __shfl_xor(s, 2);
        s += __shfl_xor(s, 4); s += __shfl_xor(s, 8);
        if (lr == 0) atomicAdd(&rowss[h * 32 + mt * 16 + lq * 4 + r], s);
      }
  }
  __syncthreads();
  if (tid < 64) {
    float v = rowss[tid];
    #pragma unroll
    for (int off = 1; off < 64; off <<= 1) v = fmaxf(v, __shfl_xor(v, off));
    if (tid == 0) atomicMax(km + (m0 >> 11), __float_as_uint(v));
  }

  #pragma unroll
  for (int mt = 0; mt < 2; ++mt) {
    const int t0 = m0 + h * 32 + mt * 16 + lq * 4;
    #pragma unroll
    for (int nt = 0; nt < 6; ++nt) {
      const int nn = g * 96 + nt * 16 + lr;
      if (nn < 256) {
        __bf16* dst = (nn < 128) ? (Kb + nn) : (Qb + (nn - 128));
        #pragma unroll
        for (int r = 0; r < 4; ++r)
          dst[(size_t)(t0 + r) * HS_N] = (__bf16)acc[mt][nt][r];
      } else {
        const int bb = t0 >> 11;
        const int tl = t0 & 2047;
        bf16x4_t o;
        #pragma unroll
        for (int r = 0; r < 4; ++r) o[r] = (__bf16)acc[mt][nt][r];
        *(bf16x4_t*)(Vt + (size_t)bb * (HS_N * SEQ_T) + (size_t)(nn - 256) * SEQ_T + tl) = o;
      }
    }
  }
}

// ---------------------------------------------------------------------------
// Kernel 2: flash attention v8 — v7 + s_setprio around MFMA clusters (T5)
// + fused merge: last-arriving block of each (b,jg) group (4 key-quarter
// parts) reduces Opart/lpart and writes the final output. Device-scope
// atomics + __threadfence for cross-XCD visibility (G16).
// ---------------------------------------------------------------------------
__global__ __launch_bounds__(256, 2) void attn_kernel(
    const __bf16* __restrict__ Qb, const __bf16* __restrict__ Kb,
    const __bf16* __restrict__ Vt, const unsigned int* __restrict__ km,
    __bf16* __restrict__ Opart, float* __restrict__ lpart,
    unsigned int* __restrict__ cnt, float* __restrict__ out) {
  __shared__ __align__(16) char smem[81920];
  __bf16* KsBase = (__bf16*)smem;                    // 2 x 16 KB
  __bf16* VsBase = (__bf16*)(smem + 32768);          // 2 x 16 KB
  float*  Ofl    = (float*)smem;                     // 128x132 fp32, post-loop

  const int lane = threadIdx.x & 63;
  const int wave = threadIdx.x >> 6;       // 0..3
  const int lr = lane & 15;
  const int lq = lane >> 4;
  const int bid  = blockIdx.x;
  const int b    = bid & 7;                // batch -> XCD pinned
  const int rest = bid >> 3;               // 0..63
  const int jg   = 15 - (rest >> 2);       // heavy-first
  const int p4   = rest & 3;               // key quarter
  const int Q0   = jg * 128;
  const int qa   = Q0 + wave * 32;         // this wave's 32 rows (2 tiles)
  const int ch   = 2 * (jg + 1);           // total 64-key chunks for this jg
  const int c0   = (p4 * ch) >> 2;         // this part's chunk range [c0,c1)
  const int c1   = ((p4 + 1) * ch) >> 2;

  const __bf16* Qbb = Qb + (size_t)b * (SEQ_T * HS_N);
  const __bf16* Kbb = Kb + (size_t)b * (SEQ_T * HS_N);
  const __bf16* Vbb = Vt + (size_t)b * (HS_N * SEQ_T);
  __bf16* pbA = (__bf16*)(smem + 65536 + wave * 4096);         // 16x64 bf16
  __bf16* pbB = (__bf16*)(smem + 65536 + wave * 4096 + 2048);  // 16x64 bf16

  bf16x8_t qf[2][4];
  #pragma unroll
  for (int t = 0; t < 2; ++t)
    #pragma unroll
    for (int ks = 0; ks < 4; ++ks)
      qf[t][ks] = *(const bf16x8_t*)(Qbb + (size_t)(qa + t * 16 + lr) * HS_N
                                     + ks * 32 + lq * 8);

  const float km2 = __uint_as_float(km[b]);
  float mrow[2][4];
  #pragma unroll
  for (int t = 0; t < 2; ++t) {
    float qn2 = 0.f;
    #pragma unroll
    for (int ks = 0; ks < 4; ++ks)
      #pragma unroll
      for (int j = 0; j < 8; ++j) { float f = (float)qf[t][ks][j]; qn2 += f * f; }
    qn2 += __shfl_xor(qn2, 16);
    qn2 += __shfl_xor(qn2, 32);
    #pragma unroll
    for (int r2 = 0; r2 < 4; ++r2)
      mrow[t][r2] = sqrtf(__shfl(qn2, lq * 4 + r2) * km2);
  }

  f32x4_t Oa[2][8];
  #pragma unroll
  for (int t = 0; t < 2; ++t)
    #pragma unroll
    for (int o = 0; o < 8; ++o) Oa[t][o] = (f32x4_t){0.f, 0.f, 0.f, 0.f};
  float lsum[2][4] = {{0.f,0.f,0.f,0.f},{0.f,0.f,0.f,0.f}};

  auto stage = [&](int bufi, int c) {
    const int kk = c * 64;
    __bf16* Ks = KsBase + bufi * 8192;
    for (int idx = wave; idx < 32; idx += 4) {   // 8 x 16B loads per wave
      if (idx < 16) {          // K: 4 rows x 256B per call
        const int row = idx * 4 + (lane >> 4);
        const int u   = (lane & 15) ^ (row & 15);
        async_cp16(Kbb + (size_t)(kk + row) * HS_N + u * 8, Ks + idx * 512);
      } else {                 // V: 8 rows x 128B per call (rows = HS dims)
        const int i2  = idx - 16;
        const int row = i2 * 8 + (lane >> 3);
        const int u   = (lane & 7) ^ (row & 7);
        async_cp16(Vbb + (size_t)row * SEQ_T + kk + u * 8, VsBase + bufi * 8192 + i2 * 512);
      }
    }
  };

  if (c0 < c1) stage(0, c0);
  __syncthreads();   // prologue: full drain once

  for (int c = c0; c < c1; ++c) {
    const int cur = (c - c0) & 1;
    if (c + 1 < c1) {
      stage(cur ^ 1, c + 1);   // 8 loads/wave stay in flight across BAR
      WAIT_VM(8);              // only chunk c's batch must be complete
    } else {
      WAIT_VM(0);
    }
    BAR();                     // all waves: buf[cur] fully written
    FENCE();

    const int kk = c * 64;
    const __bf16* Ks = KsBase + cur * 8192;
    const __bf16* Vs = VsBase + cur * 8192;

    f32x4_t s0[4], s1[4];
    #pragma unroll
    for (int nt = 0; nt < 4; ++nt) {
      s0[nt] = (f32x4_t){0.f, 0.f, 0.f, 0.f};
      s1[nt] = (f32x4_t){0.f, 0.f, 0.f, 0.f};
    }
    __builtin_amdgcn_s_setprio(1);
    #pragma unroll
    for (int ks = 0; ks < 4; ++ks)
      #pragma unroll
      for (int nt = 0; nt < 4; ++nt) {
        bf16x8_t kf = *(const bf16x8_t*)(
            &Ks[(nt * 16 + lr) * 128 + (((ks * 4 + lq) ^ lr) * 8)]);
        s0[nt] = mfma_16x16x32(qf[0][ks], kf, s0[nt]);
        s1[nt] = mfma_16x16x32(qf[1][ks], kf, s1[nt]);
      }
    __builtin_amdgcn_s_setprio(0);
    const int q0a = qa, q0b = qa + 16;
    if (kk + 63 > q0a) {
      #pragma unroll
      for (int nt = 0; nt < 4; ++nt) {
        const int col = kk + nt * 16 + lr;
        #pragma unroll
        for (int r2 = 0; r2 < 4; ++r2)
          if (col > q0a + lq * 4 + r2) s0[nt][r2] = -INFINITY;
      }
    }
    if (kk + 63 > q0b) {
      #pragma unroll
      for (int nt = 0; nt < 4; ++nt) {
        const int col = kk + nt * 16 + lr;
        #pragma unroll
        for (int r2 = 0; r2 < 4; ++r2)
          if (col > q0b + lq * 4 + r2) s1[nt][r2] = -INFINITY;
      }
    }

    #pragma unroll
    for (int r2 = 0; r2 < 4; ++r2) {
      float a0 = __expf(s0[0][r2] - mrow[0][r2]);
      float a1 = __expf(s0[1][r2] - mrow[0][r2]);
      float a2 = __expf(s0[2][r2] - mrow[0][r2]);
      float a3 = __expf(s0[3][r2] - mrow[0][r2]);
      s0[0][r2] = a0; s0[1][r2] = a1; s0[2][r2] = a2; s0[3][r2] = a3;
      lsum[0][r2] += (a0 + a1) + (a2 + a3);
      float b0 = __expf(s1[0][r2] - mrow[1][r2]);
      float b1 = __expf(s1[1][r2] - mrow[1][r2]);
      float b2 = __expf(s1[2][r2] - mrow[1][r2]);
      float b3 = __expf(s1[3][r2] - mrow[1][r2]);
      s1[0][r2] = b0; s1[1][r2] = b1; s1[2][r2] = b2; s1[3][r2] = b3;
      lsum[1][r2] += (b0 + b1) + (b2 + b3);
    }

    #pragma unroll
    for (int nt = 0; nt < 4; ++nt)
      #pragma unroll
      for (int r2 = 0; r2 < 4; ++r2) {
        const int prow = lq * 4 + r2;
        const int pcol = (nt * 16 + lr) ^ ((prow & 7) << 3);
        pbA[prow * 64 + pcol] = (__bf16)s0[nt][r2];
        pbB[prow * 64 + pcol] = (__bf16)s1[nt][r2];
      }

    #pragma unroll
    for (int k2 = 0; k2 < 2; ++k2) {
      const int au = ((k2 * 4 + lq) ^ (lr & 7)) << 3;
      bf16x8_t afrA = *(const bf16x8_t*)(pbA + lr * 64 + au);
      bf16x8_t afrB = *(const bf16x8_t*)(pbB + lr * 64 + au);
      __builtin_amdgcn_s_setprio(1);
      #pragma unroll
      for (int o = 0; o < 8; ++o) {
        bf16x8_t vfr = *(const bf16x8_t*)(
            &Vs[(o * 16 + lr) * 64 + (((k2 * 4 + lq) ^ (lr & 7)) * 8)]);
        Oa[0][o] = mfma_16x16x32(afrA, vfr, Oa[0][o]);
        Oa[1][o] = mfma_16x16x32(afrB, vfr, Oa[1][o]);
      }
      __builtin_amdgcn_s_setprio(0);
    }
    WAIT_LGKM0;                // my LDS reads (K/V/P) complete
    BAR();                     // release buf[cur] for overwrite next iter
    FENCE();
  }

  #pragma unroll
  for (int t = 0; t < 2; ++t)
    #pragma unroll
    for (int r2 = 0; r2 < 4; ++r2) {
      float v = lsum[t][r2];
      v += __shfl_xor(v, 1);
      v += __shfl_xor(v, 2);
      v += __shfl_xor(v, 4);
      v += __shfl_xor(v, 8);
      if (lr == 0)
        lpart[bid * 128 + wave * 32 + t * 16 + lq * 4 + r2] = v;
    }

  #pragma unroll
  for (int t = 0; t < 2; ++t)
    #pragma unroll
    for (int o = 0; o < 8; ++o)
      #pragma unroll
      for (int r2 = 0; r2 < 4; ++r2)
        Ofl[(wave * 32 + t * 16 + lq * 4 + r2) * 132 + o * 16 + lr] = Oa[t][o][r2];
  __syncthreads();

  {
    const int row = threadIdx.x >> 1;
    const int cb  = (threadIdx.x & 1) * 64;
    __bf16* dst = Opart + ((size_t)bid * 128 + row) * 128 + cb;
    #pragma unroll
    for (int g2 = 0; g2 < 16; ++g2) {
      float4 f = *(const float4*)(&Ofl[row * 132 + cb + g2 * 4]);
      bf16x4_t o;
      o[0] = (__bf16)f.x; o[1] = (__bf16)f.y; o[2] = (__bf16)f.z; o[3] = (__bf16)f.w;
      *(bf16x4_t*)(dst + g2 * 4) = o;
    }
  }

  // ---- fused merge: 4th arrival of group (b,jg) reduces the 4 parts ----
  __threadfence();             // my Opart/lpart stores visible device-wide
  __syncthreads();             // all threads' stores issued+fenced
  unsigned int* flagp = (unsigned int*)smem;   // Ofl reads all done
  if (threadIdx.x == 0) {
    const int gidx = (rest >> 2) * 8 + b;
    unsigned int old = atomicAdd(&cnt[gidx], 1u);
    flagp[0] = (old == 3u) ? 1u : 0u;
  }
  __syncthreads();
  if (flagp[0] != 0u) {
    __threadfence();           // acquire: see the other 3 parts' stores
    const int row = threadIdx.x >> 1;          // 0..127
    const int cb  = (threadIdx.x & 1) * 64;
    const int rbase = (rest >> 2) * 4;         // = (15-jg)*4
    int s[4];
    float l = 0.f;
    #pragma unroll
    for (int p2 = 0; p2 < 4; ++p2) {
      s[p2] = b + 8 * (rbase + p2);
      l += lpart[s[p2] * 128 + row];
    }
    const float inv = 1.0f / l;
    float* dst = out + ((size_t)b * SEQ_T + (size_t)jg * 128 + row) * HS_N + cb;
    #pragma unroll
    for (int g2 = 0; g2 < 16; ++g2) {
      float o0 = 0.f, o1 = 0.f, o2 = 0.f, o3 = 0.f;
      #pragma unroll
      for (int p2 = 0; p2 < 4; ++p2) {
        bf16x4_t a = *(const bf16x4_t*)(
            Opart + ((size_t)s[p2] * 128 + row) * 128 + cb + g2 * 4);
        o0 += (float)a[0]; o1 += (float)a[1];
        o2 += (float)a[2]; o3 += (float)a[3];
      }
      float4 o;
      o.x = o0 * inv; o.y = o1 * inv; o.z = o2 * inv; o.w = o3 * inv;
      *(float4*)(dst + g2 * 4) = o;
    }
  }
}

// ---------------------------------------------------------------------------
extern "C" void kernel_launch(void* const* d_in, const int* in_sizes, int n_in,
                              void* d_out, int out_size, void* d_ws, size_t ws_size,
                              hipStream_t stream) {
  const float* x  = (const float*)d_in[0];
  const float* Wk = (const float*)d_in[1];
  const float* Wq = (const float*)d_in[2];
  const float* Wv = (const float*)d_in[3];
  float* out = (float*)d_out;

  char* ws = (char*)d_ws;
  __bf16* Wb = (__bf16*)ws;                           //   786432 B
  __bf16* Qb = (__bf16*)(ws + 786432);                //  4194304 B
  __bf16* Kb = (__bf16*)(ws + 786432 + 4194304);      //  4194304 B
  __bf16* Vt = (__bf16*)(ws + 786432 + 8388608);      //  4194304 B
  unsigned int* km  = (unsigned int*)(ws + 13369344); //       32 B
  unsigned int* cnt = (unsigned int*)(ws + 13369408); //      512 B
  __bf16* Opart = (__bf16*)(ws + 13370368);           // 16777216 B (512x128x128)
  float*  lpart = (float*)(ws + 30147584);            //   262144 B

  castw_kernel<<<384, 256, 0, stream>>>(Wk, Wq, Wv, Wb, km, cnt);
  proj_kernel<<<256, 512, 0, stream>>>(x, Wb, Qb, Kb, Vt, km);
  attn_kernel<<<512, 256, 0, stream>>>(Qb, Kb, Vt, km, Opart, lpart, cnt, out);
}

// Round 5
// 151.283 us; speedup vs baseline: 1.6502x; 1.6502x over previous
//
#include <hip/hip_runtime.h>
#include <hip/hip_bf16.h>
#include <math.h>

#define BATCH_N 8
#define SEQ_T   2048
#define DIM_D   1024
#define HS_N    128

using bf16x8_t = __attribute__((ext_vector_type(8))) __bf16;
using bf16x4_t = __attribute__((ext_vector_type(4))) __bf16;
using f32x4_t  = __attribute__((ext_vector_type(4))) float;

__device__ __forceinline__ f32x4_t mfma_16x16x32(bf16x8_t a, bf16x8_t b, f32x4_t c) {
  return __builtin_amdgcn_mfma_f32_16x16x32_bf16(a, b, c, 0, 0, 0);
}

// async global->LDS, 16B/lane; LDS dest = wave-uniform base + lane*16
__device__ __forceinline__ void async_cp16(const void* g, void* l) {
  __builtin_amdgcn_global_load_lds(
      (const __attribute__((address_space(1))) unsigned int*)g,
      (__attribute__((address_space(3))) unsigned int*)l, 16, 0, 0);
}

// Counted-vmcnt barrier discipline (T4): never drain vmcnt(0) in main loops.
#define BAR()      __builtin_amdgcn_s_barrier()
#define FENCE()    asm volatile("" ::: "memory")
#define WAIT_VM(n) asm volatile("s_waitcnt vmcnt(" #n ")" ::: "memory")
#define WAIT_LGKM0 asm volatile("s_waitcnt lgkmcnt(0)" ::: "memory")

// ---------------------------------------------------------------------------
// Kernel 0: cast W -> bf16, rows [K:0-127][Q:128-255][V:256-383], Q pre-scaled.
// Also zeroes km.
// ---------------------------------------------------------------------------
__global__ __launch_bounds__(256) void castw_kernel(
    const float* __restrict__ Wk, const float* __restrict__ Wq,
    const float* __restrict__ Wv, __bf16* __restrict__ Wb,
    unsigned int* __restrict__ km) {
  if (blockIdx.x == 0 && threadIdx.x < 8) km[threadIdx.x] = 0u;
  int idx = blockIdx.x * 256 + threadIdx.x;
  int e   = idx * 4;
  int row = e >> 10;
  int col = e & 1023;
  const float* src;
  float sc = 1.0f;
  if (row < 128) {
    src = Wk + row * DIM_D + col;
  } else if (row < 256) {
    src = Wq + (row - 128) * DIM_D + col;
    sc  = 0.08838834764831845f;  // 1/sqrt(HS) folded into Wq
  } else {
    src = Wv + (row - 256) * DIM_D + col;
  }
  float4 v = *(const float4*)src;
  bf16x4_t o;
  o[0] = (__bf16)(v.x * sc); o[1] = (__bf16)(v.y * sc);
  o[2] = (__bf16)(v.z * sc); o[3] = (__bf16)(v.w * sc);
  *(bf16x4_t*)(Wb + e) = o;
}

// ---------------------------------------------------------------------------
// Kernel 1: projections v13 — triple-buffered B (2-iter latency cover)
// + fused knorm epilogue (per-batch max ||k||^2 via in-register acc).
// M=64 rows/block, 512 threads (8 waves = 2 m-halves x 4 n-groups), grid 256.
// B staging: stage(kt+2) each iter into buf[(kt+2)%3]; steady-state
// s_waitcnt vmcnt(6) (2 batches x 3 loads in flight), tail 3/0.
// LDS = 65536 (A: 64x512/phase) + 3x24576 (B tbuf) = 139264 -> 1 block/CU.
// ---------------------------------------------------------------------------
__global__ __launch_bounds__(512, 1) void proj_kernel(
    const float* __restrict__ x, const __bf16* __restrict__ Wb,
    __bf16* __restrict__ Qb, __bf16* __restrict__ Kb, __bf16* __restrict__ Vt,
    unsigned int* __restrict__ km) {
  __shared__ __align__(16) char psmem[139264];
  __bf16* A = (__bf16*)psmem;                       // 64 x 512 bf16 = 64 KB

  const int tid  = threadIdx.x;
  const int lane = tid & 63;
  const int wave = tid >> 6;     // 0..7
  const int h    = wave >> 2;    // m-half (0..1)
  const int g    = wave & 3;     // n-group (0..3)
  const int lr = lane & 15;
  const int lq = lane >> 4;
  const int m0 = blockIdx.x * 64;

  f32x4_t acc[2][6];
  #pragma unroll
  for (int mt = 0; mt < 2; ++mt)
    #pragma unroll
    for (int nt = 0; nt < 6; ++nt) acc[mt][nt] = (f32x4_t){0.f, 0.f, 0.f, 0.f};

  auto stageB = [&](int kt) {
    __bf16* Bs = (__bf16*)(psmem + 65536 + (kt % 3) * 24576);
    for (int c = wave; c < 24; c += 8) {     // 3 x 16B loads per wave
      const int row = c * 16 + (lane >> 2);
      const int u   = (lane & 3) ^ ((row >> 1) & 3);
      async_cp16(Wb + (size_t)row * DIM_D + kt * 32 + u * 8, Bs + c * 512);
    }
  };

  stageB(0);
  stageB(1);

  for (int p = 0; p < 2; ++p) {
    __syncthreads();   // phase boundary: full drain OK (2x/kernel)

    // ---- cast this phase's x slab (64 rows x 512 cols) fp32->bf16 into LDS ----
    {
      const int r  = tid >> 3;        // 0..63
      const int t  = tid & 7;
      const float* xs = x + (size_t)(m0 + r) * DIM_D + p * 512;
      __bf16* as = A + r * 512;
      const int sw = r & 7;
      #pragma unroll
      for (int i = 0; i < 8; ++i) {
        const int u = t + 8 * i;      // 16B units (8 bf16) within the phase
        float4 f0 = *(const float4*)(xs + u * 8);
        float4 f1 = *(const float4*)(xs + u * 8 + 4);
        bf16x8_t a;
        a[0] = (__bf16)f0.x; a[1] = (__bf16)f0.y;
        a[2] = (__bf16)f0.z; a[3] = (__bf16)f0.w;
        a[4] = (__bf16)f1.x; a[5] = (__bf16)f1.y;
        a[6] = (__bf16)f1.z; a[7] = (__bf16)f1.w;
        *(bf16x8_t*)(as + ((u ^ sw) * 8)) = a;
      }
    }
    __syncthreads();   // A ready

    for (int kt2 = 0; kt2 < 16; ++kt2) {
      const int kt = p * 16 + kt2;
      if (kt + 2 < 32) stageB(kt + 2);   // depth-2 prefetch stays in flight
      if (kt < 30)       { WAIT_VM(6); } // batches kt+1, kt+2 in flight
      else if (kt == 30) { WAIT_VM(3); } // only batch 31 younger
      else               { WAIT_VM(0); }
      BAR();                             // all waves: buf[kt%3] fully written
      FENCE();
      const __bf16* Bs = (const __bf16*)(psmem + 65536 + (kt % 3) * 24576);

      bf16x8_t af[2];
      #pragma unroll
      for (int mt = 0; mt < 2; ++mt) {
        const int ml = h * 32 + mt * 16 + lr;
        const int u  = kt2 * 4 + lq;
        af[mt] = *(const bf16x8_t*)(&A[ml * 512 + ((u ^ (ml & 7)) * 8)]);
      }
      bf16x8_t bfv[6];
      #pragma unroll
      for (int nt = 0; nt < 6; ++nt) {
        const int nl = g * 96 + nt * 16 + lr;
        bfv[nt] = *(const bf16x8_t*)(&Bs[nl * 32 + ((lq ^ ((nl >> 1) & 3)) * 8)]);
      }
      #pragma unroll
      for (int mt = 0; mt < 2; ++mt)
        #pragma unroll
        for (int nt = 0; nt < 6; ++nt)
          acc[mt][nt] = mfma_16x16x32(af[mt], bfv[nt], acc[mt][nt]);
      WAIT_LGKM0;                    // my LDS reads landed in regs
      BAR();                         // release buf[(kt+2)%3] target for next iter
      FENCE();
    }
  }

  // ---- fused knorm: this block computes ALL 128 K-cols of rows m0..m0+63 ----
  __syncthreads();
  float* rowss = (float*)psmem;      // A region dead; reuse 64 floats
  if (tid < 64) rowss[tid] = 0.f;
  __syncthreads();
  if (g < 2) {                       // K cols live in g=0 (0..95), g=1 nt<2 (96..127)
    #pragma unroll
    for (int mt = 0; mt < 2; ++mt)
      #pragma unroll
      for (int r = 0; r < 4; ++r) {
        float s = 0.f;
        #pragma unroll
        for (int nt = 0; nt < 6; ++nt)
          if (g == 0 || nt < 2) s += acc[mt][nt][r] * acc[mt][nt][r];
        s += __shfl_xor(s, 1); s += __shfl_xor(s, 2);
        s += __shfl_xor(s, 4); s += __shfl_xor(s, 8);
        if (lr == 0) atomicAdd(&rowss[h * 32 + mt * 16 + lq * 4 + r], s);
      }
  }
  __syncthreads();
  if (tid < 64) {
    float v = rowss[tid];
    #pragma unroll
    for (int off = 1; off < 64; off <<= 1) v = fmaxf(v, __shfl_xor(v, off));
    if (tid == 0) atomicMax(km + (m0 >> 11), __float_as_uint(v));
  }

  #pragma unroll
  for (int mt = 0; mt < 2; ++mt) {
    const int t0 = m0 + h * 32 + mt * 16 + lq * 4;
    #pragma unroll
    for (int nt = 0; nt < 6; ++nt) {
      const int nn = g * 96 + nt * 16 + lr;
      if (nn < 256) {
        __bf16* dst = (nn < 128) ? (Kb + nn) : (Qb + (nn - 128));
        #pragma unroll
        for (int r = 0; r < 4; ++r)
          dst[(size_t)(t0 + r) * HS_N] = (__bf16)acc[mt][nt][r];
      } else {
        const int bb = t0 >> 11;
        const int tl = t0 & 2047;
        bf16x4_t o;
        #pragma unroll
        for (int r = 0; r < 4; ++r) o[r] = (__bf16)acc[mt][nt][r];
        *(bf16x4_t*)(Vt + (size_t)bb * (HS_N * SEQ_T) + (size_t)(nn - 256) * SEQ_T + tl) = o;
      }
    }
  }
}

// ---------------------------------------------------------------------------
// Kernel 2: flash attention v7 (R3-verified). Grid 512: bid = b + 8*rest,
// rest = (15-jg)*4 + p4 (heavy-first). Each block owns a quarter of q-tile
// jg's key range. LDS 81920 -> 2 blocks/CU. Counted vmcnt(8) + dual raw
// barriers per chunk. No device-scope fences (merge is a separate kernel:
// the dispatch boundary provides coherence for free, R4 lesson).
// ---------------------------------------------------------------------------
__global__ __launch_bounds__(256, 2) void attn_kernel(
    const __bf16* __restrict__ Qb, const __bf16* __restrict__ Kb,
    const __bf16* __restrict__ Vt, const unsigned int* __restrict__ km,
    __bf16* __restrict__ Opart, float* __restrict__ lpart) {
  __shared__ __align__(16) char smem[81920];
  __bf16* KsBase = (__bf16*)smem;                    // 2 x 16 KB
  __bf16* VsBase = (__bf16*)(smem + 32768);          // 2 x 16 KB
  float*  Ofl    = (float*)smem;                     // 128x132 fp32, post-loop

  const int lane = threadIdx.x & 63;
  const int wave = threadIdx.x >> 6;       // 0..3
  const int lr = lane & 15;
  const int lq = lane >> 4;
  const int bid  = blockIdx.x;
  const int b    = bid & 7;                // batch -> XCD pinned
  const int rest = bid >> 3;               // 0..63
  const int jg   = 15 - (rest >> 2);       // heavy-first
  const int p4   = rest & 3;               // key quarter
  const int Q0   = jg * 128;
  const int qa   = Q0 + wave * 32;         // this wave's 32 rows (2 tiles)
  const int ch   = 2 * (jg + 1);           // total 64-key chunks for this jg
  const int c0   = (p4 * ch) >> 2;         // this part's chunk range [c0,c1)
  const int c1   = ((p4 + 1) * ch) >> 2;

  const __bf16* Qbb = Qb + (size_t)b * (SEQ_T * HS_N);
  const __bf16* Kbb = Kb + (size_t)b * (SEQ_T * HS_N);
  const __bf16* Vbb = Vt + (size_t)b * (HS_N * SEQ_T);
  __bf16* pbA = (__bf16*)(smem + 65536 + wave * 4096);         // 16x64 bf16
  __bf16* pbB = (__bf16*)(smem + 65536 + wave * 4096 + 2048);  // 16x64 bf16

  bf16x8_t qf[2][4];
  #pragma unroll
  for (int t = 0; t < 2; ++t)
    #pragma unroll
    for (int ks = 0; ks < 4; ++ks)
      qf[t][ks] = *(const bf16x8_t*)(Qbb + (size_t)(qa + t * 16 + lr) * HS_N
                                     + ks * 32 + lq * 8);

  const float km2 = __uint_as_float(km[b]);
  float mrow[2][4];
  #pragma unroll
  for (int t = 0; t < 2; ++t) {
    float qn2 = 0.f;
    #pragma unroll
    for (int ks = 0; ks < 4; ++ks)
      #pragma unroll
      for (int j = 0; j < 8; ++j) { float f = (float)qf[t][ks][j]; qn2 += f * f; }
    qn2 += __shfl_xor(qn2, 16);
    qn2 += __shfl_xor(qn2, 32);
    #pragma unroll
    for (int r2 = 0; r2 < 4; ++r2)
      mrow[t][r2] = sqrtf(__shfl(qn2, lq * 4 + r2) * km2);
  }

  f32x4_t Oa[2][8];
  #pragma unroll
  for (int t = 0; t < 2; ++t)
    #pragma unroll
    for (int o = 0; o < 8; ++o) Oa[t][o] = (f32x4_t){0.f, 0.f, 0.f, 0.f};
  float lsum[2][4] = {{0.f,0.f,0.f,0.f},{0.f,0.f,0.f,0.f}};

  auto stage = [&](int bufi, int c) {
    const int kk = c * 64;
    __bf16* Ks = KsBase + bufi * 8192;
    for (int idx = wave; idx < 32; idx += 4) {   // 8 x 16B loads per wave
      if (idx < 16) {          // K: 4 rows x 256B per call
        const int row = idx * 4 + (lane >> 4);
        const int u   = (lane & 15) ^ (row & 15);
        async_cp16(Kbb + (size_t)(kk + row) * HS_N + u * 8, Ks + idx * 512);
      } else {                 // V: 8 rows x 128B per call (rows = HS dims)
        const int i2  = idx - 16;
        const int row = i2 * 8 + (lane >> 3);
        const int u   = (lane & 7) ^ (row & 7);
        async_cp16(Vbb + (size_t)row * SEQ_T + kk + u * 8, VsBase + bufi * 8192 + i2 * 512);
      }
    }
  };

  if (c0 < c1) stage(0, c0);
  __syncthreads();   // prologue: full drain once

  for (int c = c0; c < c1; ++c) {
    const int cur = (c - c0) & 1;
    if (c + 1 < c1) {
      stage(cur ^ 1, c + 1);   // 8 loads/wave stay in flight across BAR
      WAIT_VM(8);              // only chunk c's batch must be complete
    } else {
      WAIT_VM(0);
    }
    BAR();                     // all waves: buf[cur] fully written
    FENCE();

    const int kk = c * 64;
    const __bf16* Ks = KsBase + cur * 8192;
    const __bf16* Vs = VsBase + cur * 8192;

    f32x4_t s0[4], s1[4];
    #pragma unroll
    for (int nt = 0; nt < 4; ++nt) {
      s0[nt] = (f32x4_t){0.f, 0.f, 0.f, 0.f};
      s1[nt] = (f32x4_t){0.f, 0.f, 0.f, 0.f};
    }
    #pragma unroll
    for (int ks = 0; ks < 4; ++ks)
      #pragma unroll
      for (int nt = 0; nt < 4; ++nt) {
        bf16x8_t kf = *(const bf16x8_t*)(
            &Ks[(nt * 16 + lr) * 128 + (((ks * 4 + lq) ^ lr) * 8)]);
        s0[nt] = mfma_16x16x32(qf[0][ks], kf, s0[nt]);
        s1[nt] = mfma_16x16x32(qf[1][ks], kf, s1[nt]);
      }
    const int q0a = qa, q0b = qa + 16;
    if (kk + 63 > q0a) {
      #pragma unroll
      for (int nt = 0; nt < 4; ++nt) {
        const int col = kk + nt * 16 + lr;
        #pragma unroll
        for (int r2 = 0; r2 < 4; ++r2)
          if (col > q0a + lq * 4 + r2) s0[nt][r2] = -INFINITY;
      }
    }
    if (kk + 63 > q0b) {
      #pragma unroll
      for (int nt = 0; nt < 4; ++nt) {
        const int col = kk + nt * 16 + lr;
        #pragma unroll
        for (int r2 = 0; r2 < 4; ++r2)
          if (col > q0b + lq * 4 + r2) s1[nt][r2] = -INFINITY;
      }
    }

    #pragma unroll
    for (int r2 = 0; r2 < 4; ++r2) {
      float a0 = __expf(s0[0][r2] - mrow[0][r2]);
      float a1 = __expf(s0[1][r2] - mrow[0][r2]);
      float a2 = __expf(s0[2][r2] - mrow[0][r2]);
      float a3 = __expf(s0[3][r2] - mrow[0][r2]);
      s0[0][r2] = a0; s0[1][r2] = a1; s0[2][r2] = a2; s0[3][r2] = a3;
      lsum[0][r2] += (a0 + a1) + (a2 + a3);
      float b0 = __expf(s1[0][r2] - mrow[1][r2]);
      float b1 = __expf(s1[1][r2] - mrow[1][r2]);
      float b2 = __expf(s1[2][r2] - mrow[1][r2]);
      float b3 = __expf(s1[3][r2] - mrow[1][r2]);
      s1[0][r2] = b0; s1[1][r2] = b1; s1[2][r2] = b2; s1[3][r2] = b3;
      lsum[1][r2] += (b0 + b1) + (b2 + b3);
    }

    #pragma unroll
    for (int nt = 0; nt < 4; ++nt)
      #pragma unroll
      for (int r2 = 0; r2 < 4; ++r2) {
        const int prow = lq * 4 + r2;
        const int pcol = (nt * 16 + lr) ^ ((prow & 7) << 3);
        pbA[prow * 64 + pcol] = (__bf16)s0[nt][r2];
        pbB[prow * 64 + pcol] = (__bf16)s1[nt][r2];
      }

    #pragma unroll
    for (int k2 = 0; k2 < 2; ++k2) {
      const int au = ((k2 * 4 + lq) ^ (lr & 7)) << 3;
      bf16x8_t afrA = *(const bf16x8_t*)(pbA + lr * 64 + au);
      bf16x8_t afrB = *(const bf16x8_t*)(pbB + lr * 64 + au);
      #pragma unroll
      for (int o = 0; o < 8; ++o) {
        bf16x8_t vfr = *(const bf16x8_t*)(
            &Vs[(o * 16 + lr) * 64 + (((k2 * 4 + lq) ^ (lr & 7)) * 8)]);
        Oa[0][o] = mfma_16x16x32(afrA, vfr, Oa[0][o]);
        Oa[1][o] = mfma_16x16x32(afrB, vfr, Oa[1][o]);
      }
    }
    WAIT_LGKM0;                // my LDS reads (K/V/P) complete
    BAR();                     // release buf[cur] for overwrite next iter
    FENCE();
  }

  #pragma unroll
  for (int t = 0; t < 2; ++t)
    #pragma unroll
    for (int r2 = 0; r2 < 4; ++r2) {
      float v = lsum[t][r2];
      v += __shfl_xor(v, 1);
      v += __shfl_xor(v, 2);
      v += __shfl_xor(v, 4);
      v += __shfl_xor(v, 8);
      if (lr == 0)
        lpart[bid * 128 + wave * 32 + t * 16 + lq * 4 + r2] = v;
    }

  #pragma unroll
  for (int t = 0; t < 2; ++t)
    #pragma unroll
    for (int o = 0; o < 8; ++o)
      #pragma unroll
      for (int r2 = 0; r2 < 4; ++r2)
        Ofl[(wave * 32 + t * 16 + lq * 4 + r2) * 132 + o * 16 + lr] = Oa[t][o][r2];
  __syncthreads();

  {
    const int row = threadIdx.x >> 1;
    const int cb  = (threadIdx.x & 1) * 64;
    __bf16* dst = Opart + ((size_t)bid * 128 + row) * 128 + cb;
    #pragma unroll
    for (int g2 = 0; g2 < 16; ++g2) {
      float4 f = *(const float4*)(&Ofl[row * 132 + cb + g2 * 4]);
      bf16x4_t o;
      o[0] = (__bf16)f.x; o[1] = (__bf16)f.y; o[2] = (__bf16)f.z; o[3] = (__bf16)f.w;
      *(bf16x4_t*)(dst + g2 * 4) = o;
    }
  }
}

// ---------------------------------------------------------------------------
// Kernel 3: merge the 4 key-quarters: out = (sum O_p) / (sum l_p)
// ---------------------------------------------------------------------------
__global__ __launch_bounds__(256) void merge_kernel(
    const __bf16* __restrict__ Opart, const float* __restrict__ lpart,
    float* __restrict__ out) {
  const int idx = blockIdx.x * 256 + threadIdx.x;   // 524288 threads
  const int row = idx >> 5;                         // global row 0..16383
  const int c4  = (idx & 31) * 4;
  const int b   = row >> 11;
  const int tl  = row & 2047;
  const int jg  = tl >> 7;
  const int lrow = tl & 127;
  const int rbase = (15 - jg) * 4;
  float a0 = 0.f, a1 = 0.f, a2 = 0.f, a3 = 0.f, l = 0.f;
  #pragma unroll
  for (int p = 0; p < 4; ++p) {
    const int s = b + 8 * (rbase + p);
    bf16x4_t a = *(const bf16x4_t*)(Opart + ((size_t)s * 128 + lrow) * 128 + c4);
    a0 += (float)a[0]; a1 += (float)a[1]; a2 += (float)a[2]; a3 += (float)a[3];
    l += lpart[s * 128 + lrow];
  }
  const float inv = 1.0f / l;
  float4 o;
  o.x = a0 * inv; o.y = a1 * inv; o.z = a2 * inv; o.w = a3 * inv;
  *(float4*)(out + (size_t)row * HS_N + c4) = o;
}

// ---------------------------------------------------------------------------
extern "C" void kernel_launch(void* const* d_in, const int* in_sizes, int n_in,
                              void* d_out, int out_size, void* d_ws, size_t ws_size,
                              hipStream_t stream) {
  const float* x  = (const float*)d_in[0];
  const float* Wk = (const float*)d_in[1];
  const float* Wq = (const float*)d_in[2];
  const float* Wv = (const float*)d_in[3];
  float* out = (float*)d_out;

  char* ws = (char*)d_ws;
  __bf16* Wb = (__bf16*)ws;                          //   786432 B
  __bf16* Qb = (__bf16*)(ws + 786432);               //  4194304 B
  __bf16* Kb = (__bf16*)(ws + 786432 + 4194304);     //  4194304 B
  __bf16* Vt = (__bf16*)(ws + 786432 + 8388608);     //  4194304 B
  unsigned int* km = (unsigned int*)(ws + 13369344); //       32 B
  __bf16* Opart = (__bf16*)(ws + 13369600);          // 16777216 B (512x128x128)
  float*  lpart = (float*)(ws + 30146816);           //   262144 B

  castw_kernel<<<384, 256, 0, stream>>>(Wk, Wq, Wv, Wb, km);
  proj_kernel<<<256, 512, 0, stream>>>(x, Wb, Qb, Kb, Vt, km);
  attn_kernel<<<512, 256, 0, stream>>>(Qb, Kb, Vt, km, Opart, lpart);
  merge_kernel<<<2048, 256, 0, stream>>>(Opart, lpart, out);
}